// Round 5
// baseline (121.138 us; speedup 1.0000x reference)
//
#include <hip/hip_runtime.h>

// RWKV-4 WKV forward. B=16, T=1024, C=2048, fp32.
// T-split chunked scan: block = 8 waves x 64 channels. Each 128-t segment is
// split 8 waves x 16 t held in registers (double-buffered). Per segment:
//   A: per-wave summary transform (P,Q,O) from empty state -> LDS
//   barrier
//   B: compose running state with prefix of earlier waves' transforms,
//      replay the 16 reg-held steps -> y; wave 7's post-state = new running
//      state (double-buffered slots => single barrier per segment).
// Occupancy 16 waves/CU (vs 2 for the pure channel-parallel kernel).

#define T_DIM 1024
#define CHUNK 16
#define WAVES 8
#define SEG   (WAVES * CHUNK)   // 128
#define NSEG  (T_DIM / SEG)     // 8
#define NEG_BIG -1e38f

__global__ __launch_bounds__(WAVES * 64, 4) void wkv_fwd_kernel(
    const float* __restrict__ w, const float* __restrict__ u,
    const float* __restrict__ kk, const float* __restrict__ vv,
    float* __restrict__ y, int C)
{
    __shared__ float Tp[2][WAVES][64], Tq[2][WAVES][64], To[2][WAVES][64];
    __shared__ float Sp[2][64], Sq[2][64], So[2][64];

    const int lane = threadIdx.x & 63;
    const int wid  = threadIdx.x >> 6;
    const int c    = blockIdx.x * 64 + lane;
    const int b    = blockIdx.y;

    const float wc  = w[c];
    const float uc  = u[c];
    const float wCH = wc * (float)CHUNK;

    const size_t base = (size_t)b * T_DIM * C + c;   // + t*C
    const float* kp = kk + base;
    const float* vp = vv + base;
    float*       yp = y  + base;

    if (wid == 0) { Sp[0][lane] = 0.f; Sq[0][lane] = 0.f; So[0][lane] = NEG_BIG; }

    float kA[CHUNK], vA[CHUNK], kB[CHUNK], vB[CHUNK];

    // prologue: segment 0 -> A, segment 1 -> B (64 coalesced dword loads)
    {
        const size_t t0 = (size_t)wid * CHUNK;
#pragma unroll
        for (int j = 0; j < CHUNK; ++j) { kA[j] = kp[(t0 + j) * C]; vA[j] = vp[(t0 + j) * C]; }
        const size_t t1 = t0 + SEG;
#pragma unroll
        for (int j = 0; j < CHUNK; ++j) { kB[j] = kp[(t1 + j) * C]; vB[j] = vp[(t1 + j) * C]; }
    }
    __builtin_amdgcn_sched_barrier(0);

    auto body = [&](int s, float (&kc)[CHUNK], float (&vc)[CHUNK]) {
        const int sl = s & 1;

        // --- phase A: summary transform of this wave's chunk from empty state
        float P = 0.f, Q = 0.f, O = NEG_BIG;
#pragma unroll
        for (int j = 0; j < CHUNK; ++j) {
            const float kt = kc[j], vt = vc[j];
            const float wo = O + wc;
            const float d  = wo - kt;
            const float e  = __expf(-fabsf(d));
            const float A2 = d >= 0.f ? 1.f : e;
            const float E2 = d >= 0.f ? e : 1.f;
            P = fmaf(A2, P, E2 * vt);
            Q = fmaf(A2, Q, E2);
            O = fmaxf(wo, kt);
        }
        if (wid < WAVES - 1) {
            Tp[sl][wid][lane] = P; Tq[sl][wid][lane] = Q; To[sl][wid][lane] = O;
        }
        __syncthreads();

        // --- phase B: compose S_in = S_run ∘ T_0 ∘ ... ∘ T_{wid-1}
        float p = Sp[sl][lane], q = Sq[sl][lane], o = So[sl][lane];
        for (int j = 0; j < wid; ++j) {       // wave-uniform trip count
            const float Oj = To[sl][j][lane];
            const float a  = o + wCH;         // CHUNK decay steps on history
            const float d  = a - Oj;
            const float on = fmaxf(a, Oj);
            const float e  = __expf(-fabsf(d));
            const float sA = d >= 0.f ? 1.f : e;
            const float sB = d >= 0.f ? e : 1.f;
            p = fmaf(sA, p, sB * Tp[sl][j][lane]);
            q = fmaf(sA, q, sB * Tq[sl][j][lane]);
            o = on;
        }

        // --- replay the reg-held chunk from the true incoming state, emit y
        const size_t tbase = (size_t)s * SEG + (size_t)wid * CHUNK;
#pragma unroll
        for (int j = 0; j < CHUNK; ++j) {
            const float kt = kc[j], vt = vc[j];
            const float uk = uc + kt;
            const float dd = o - uk;
            const float e1 = __expf(-fabsf(dd));
            const float A  = dd >= 0.f ? 1.f : e1;
            const float E  = dd >= 0.f ? e1 : 1.f;
            yp[(tbase + j) * C] = __fdividef(fmaf(A, p, E * vt), fmaf(A, q, E));

            const float wo = wc + o;
            const float d2 = wo - kt;
            const float e2 = __expf(-fabsf(d2));
            const float A2 = d2 >= 0.f ? 1.f : e2;
            const float E2 = d2 >= 0.f ? e2 : 1.f;
            p = fmaf(A2, p, E2 * vt);
            q = fmaf(A2, q, E2);
            o = fmaxf(wo, kt);
        }
        if (wid == WAVES - 1) {   // post-replay state of last wave = new S_run
            Sp[1 - sl][lane] = p; Sq[1 - sl][lane] = q; So[1 - sl][lane] = o;
        }

        // --- prefetch segment s+2 into the buffer just freed
        if (s + 2 < NSEG) {
            const size_t tn = tbase + 2 * SEG;
#pragma unroll
            for (int j = 0; j < CHUNK; ++j) { kc[j] = kp[(tn + j) * C]; vc[j] = vp[(tn + j) * C]; }
        }
        __builtin_amdgcn_sched_barrier(0);
    };

#pragma unroll 1
    for (int s2 = 0; s2 < NSEG; s2 += 2) {
        body(s2,     kA, vA);
        body(s2 + 1, kB, vB);
    }
}

extern "C" void kernel_launch(void* const* d_in, const int* in_sizes, int n_in,
                              void* d_out, int out_size, void* d_ws, size_t ws_size,
                              hipStream_t stream) {
    // inputs: 0=B, 1=T, 2=C (scalars), 3=w[C], 4=u[C], 5=k[B*T*C], 6=v[B*T*C]
    const float* w = (const float*)d_in[3];
    const float* u = (const float*)d_in[4];
    const float* k = (const float*)d_in[5];
    const float* v = (const float*)d_in[6];
    float* y = (float*)d_out;

    const int C = in_sizes[3];                 // 2048
    const int B = in_sizes[5] / (T_DIM * C);   // 16

    dim3 grid(C / 64, B);
    dim3 block(WAVES * 64);
    wkv_fwd_kernel<<<grid, block, 0, stream>>>(w, u, k, v, y, C);
}

// Round 6
// 97.959 us; speedup vs baseline: 1.2366x; 1.2366x over previous
//
#include <hip/hip_runtime.h>

// RWKV-4 WKV forward. B=16, T=1024, C=2048, fp32.
// T-split chunked scan: block = 8 waves x 64 channels. Each 64-t segment is
// split 8 waves x 8 t held in registers (double-buffered, 32 floats total ->
// fits the 64-VGPR/8-wave operating point, no spill). Per segment:
//   A: per-wave summary transform (P,Q,O) from empty state -> LDS
//   barrier
//   B: compose running state with prefix of earlier waves' transforms,
//      replay the 8 reg-held steps -> y; wave 7's post-state = new running
//      state (double-buffered slots => single barrier per segment).

#define T_DIM 1024
#define CHUNK 8
#define WAVES 8
#define SEG   (WAVES * CHUNK)   // 64
#define NSEG  (T_DIM / SEG)     // 16
#define NEG_BIG -1e38f

__global__ __launch_bounds__(WAVES * 64, 4) void wkv_fwd_kernel(
    const float* __restrict__ w, const float* __restrict__ u,
    const float* __restrict__ kk, const float* __restrict__ vv,
    float* __restrict__ y, int C)
{
    __shared__ float Tp[2][WAVES][64], Tq[2][WAVES][64], To[2][WAVES][64];
    __shared__ float Sp[2][64], Sq[2][64], So[2][64];

    const int lane = threadIdx.x & 63;
    const int wid  = threadIdx.x >> 6;
    const int c    = blockIdx.x * 64 + lane;
    const int b    = blockIdx.y;

    const float wc  = w[c];
    const float uc  = u[c];
    const float wCH = wc * (float)CHUNK;

    const size_t base = (size_t)b * T_DIM * C + c;   // + t*C
    const float* kp = kk + base;
    const float* vp = vv + base;
    float*       yp = y  + base;

    if (wid == 0) { Sp[0][lane] = 0.f; Sq[0][lane] = 0.f; So[0][lane] = NEG_BIG; }

    float k0[CHUNK], v0[CHUNK], k1[CHUNK], v1[CHUNK];

    // prologue: segment 0 -> buf0, segment 1 -> buf1 (coalesced 256B wave loads)
    {
        const int t0 = wid * CHUNK;
#pragma unroll
        for (int j = 0; j < CHUNK; ++j) { k0[j] = kp[(t0 + j) * C];       v0[j] = vp[(t0 + j) * C]; }
#pragma unroll
        for (int j = 0; j < CHUNK; ++j) { k1[j] = kp[(t0 + SEG + j) * C]; v1[j] = vp[(t0 + SEG + j) * C]; }
    }
    __builtin_amdgcn_sched_barrier(0);

    auto body = [&](int s, float (&kc)[CHUNK], float (&vc)[CHUNK]) {
        const int sl = s & 1;

        // --- phase A: summary transform of this wave's chunk from empty state
        float P = 0.f, Q = 0.f, O = NEG_BIG;
#pragma unroll
        for (int j = 0; j < CHUNK; ++j) {
            const float kt = kc[j], vt = vc[j];
            const float wo = O + wc;
            const float d  = wo - kt;
            const float e  = __expf(-fabsf(d));
            const float A2 = d >= 0.f ? 1.f : e;
            const float E2 = d >= 0.f ? e : 1.f;
            P = fmaf(A2, P, E2 * vt);
            Q = fmaf(A2, Q, E2);
            O = fmaxf(wo, kt);
        }
        if (wid < WAVES - 1) {
            Tp[sl][wid][lane] = P; Tq[sl][wid][lane] = Q; To[sl][wid][lane] = O;
        }
        __syncthreads();

        // --- phase B: compose S_in = S_run ∘ T_0 ∘ ... ∘ T_{wid-1}
        float p = Sp[sl][lane], q = Sq[sl][lane], o = So[sl][lane];
        for (int j = 0; j < wid; ++j) {       // wave-uniform trip count
            const float Oj = To[sl][j][lane];
            const float a  = o + wCH;         // CHUNK decay steps on history
            const float d  = a - Oj;
            const float on = fmaxf(a, Oj);
            const float e  = __expf(-fabsf(d));
            const float sA = d >= 0.f ? 1.f : e;
            const float sB = d >= 0.f ? e : 1.f;
            p = fmaf(sA, p, sB * Tp[sl][j][lane]);
            q = fmaf(sA, q, sB * Tq[sl][j][lane]);
            o = on;
        }

        // --- replay the reg-held chunk from the true incoming state, emit y
        const int tbase = s * SEG + wid * CHUNK;
#pragma unroll
        for (int j = 0; j < CHUNK; ++j) {
            const float kt = kc[j], vt = vc[j];
            const float uk = uc + kt;
            const float dd = o - uk;
            const float e1 = __expf(-fabsf(dd));
            const float A  = dd >= 0.f ? 1.f : e1;
            const float E  = dd >= 0.f ? e1 : 1.f;
            yp[(size_t)(tbase + j) * C] = __fdividef(fmaf(A, p, E * vt), fmaf(A, q, E));

            const float wo = wc + o;
            const float d2 = wo - kt;
            const float e2 = __expf(-fabsf(d2));
            const float A2 = d2 >= 0.f ? 1.f : e2;
            const float E2 = d2 >= 0.f ? e2 : 1.f;
            p = fmaf(A2, p, E2 * vt);
            q = fmaf(A2, q, E2);
            o = fmaxf(wo, kt);
        }
        if (wid == WAVES - 1) {   // post-replay state of last wave = new S_run
            Sp[1 - sl][lane] = p; Sq[1 - sl][lane] = q; So[1 - sl][lane] = o;
        }

        // --- prefetch segment s+2 into the buffer just freed
        if (s + 2 < NSEG) {
            const int tn = tbase + 2 * SEG;
#pragma unroll
            for (int j = 0; j < CHUNK; ++j) { kc[j] = kp[(tn + j) * C]; vc[j] = vp[(tn + j) * C]; }
        }
        __builtin_amdgcn_sched_barrier(0);
    };

#pragma unroll 1
    for (int s2 = 0; s2 < NSEG; s2 += 2) {
        body(s2,     k0, v0);
        body(s2 + 1, k1, v1);
    }
}

extern "C" void kernel_launch(void* const* d_in, const int* in_sizes, int n_in,
                              void* d_out, int out_size, void* d_ws, size_t ws_size,
                              hipStream_t stream) {
    // inputs: 0=B, 1=T, 2=C (scalars), 3=w[C], 4=u[C], 5=k[B*T*C], 6=v[B*T*C]
    const float* w = (const float*)d_in[3];
    const float* u = (const float*)d_in[4];
    const float* k = (const float*)d_in[5];
    const float* v = (const float*)d_in[6];
    float* y = (float*)d_out;

    const int C = in_sizes[3];                 // 2048
    const int B = in_sizes[5] / (T_DIM * C);   // 16

    dim3 grid(C / 64, B);
    dim3 block(WAVES * 64);
    wkv_fwd_kernel<<<grid, block, 0, stream>>>(w, u, k, v, y, C);
}

// Round 7
// 96.138 us; speedup vs baseline: 1.2600x; 1.0190x over previous
//
#include <hip/hip_runtime.h>

// RWKV-4 WKV forward. B=16, T=1024, C=2048, fp32.
// T-split chunked scan, z-space formulation. Block = 8 waves x 64 channels;
// each 64-t segment = 8 waves x 8 t in registers (double-buffered).
// z_j = k_j - j*w folds the decay into the index, so per chunk:
//   - exclusive prefix max M_j: pure v_max chain (no exp on the chain)
//   - rescale factors c_j, d_j: independent exps (off critical path)
//   - P/Q accumulators: pure fma chains (dual-chain ILP)
//   - y_j uses exact normalizer no = max3(o+jw, (j-1)w+M_j, u+k_j):
//     all terms <= 1, dominant branch factor >= 1 -> no NaN/overflow.
// Phase A (summaries) and replay merge into one pass; 1 barrier/segment.

#define T_DIM 1024
#define CDIM  2048
#define CHUNK 8
#define WAVES 8
#define SEG   (WAVES * CHUNK)   // 64
#define NSEG  (T_DIM / SEG)     // 16
#define NEG_BIG -1e38f

__global__ __launch_bounds__(WAVES * 64, 4) void wkv_fwd_kernel(
    const float* __restrict__ w, const float* __restrict__ u,
    const float* __restrict__ kk, const float* __restrict__ vv,
    float* __restrict__ y)
{
    __shared__ float Tp[2][WAVES][64], Tq[2][WAVES][64], To[2][WAVES][64];
    __shared__ float Sp[2][64], Sq[2][64], So[2][64];

    const int lane = threadIdx.x & 63;
    const int wid  = threadIdx.x >> 6;
    const int c    = blockIdx.x * 64 + lane;
    const int b    = blockIdx.y;

    const float wc  = w[c];
    const float uc  = u[c];
    const float wCH = wc * (float)CHUNK;

    const size_t base = (size_t)b * T_DIM * CDIM + c;   // + t*CDIM
    const float* kp = kk + base;
    const float* vp = vv + base;
    float*       yp = y  + base;

    if (wid == 0) { Sp[0][lane] = 0.f; Sq[0][lane] = 0.f; So[0][lane] = NEG_BIG; }

    float k0[CHUNK], v0[CHUNK], k1[CHUNK], v1[CHUNK];

    // prologue: segment 0 -> buf0, segment 1 -> buf1 (coalesced wave loads)
    {
        const int t0 = wid * CHUNK;
#pragma unroll
        for (int j = 0; j < CHUNK; ++j) { k0[j] = kp[(size_t)(t0 + j) * CDIM];       v0[j] = vp[(size_t)(t0 + j) * CDIM]; }
#pragma unroll
        for (int j = 0; j < CHUNK; ++j) { k1[j] = kp[(size_t)(t0 + SEG + j) * CDIM]; v1[j] = vp[(size_t)(t0 + SEG + j) * CDIM]; }
    }
    __builtin_amdgcn_sched_barrier(0);

    auto body = [&](int s, float (&kc)[CHUNK], float (&vc)[CHUNK]) {
        const int sl = s & 1;

        // z-space precompute (all independent except the short max chain)
        float uk[CHUNK], hh[CHUNK], cf[CHUNK], df[CHUNK];
        float M = NEG_BIG;
#pragma unroll
        for (int j = 0; j < CHUNK; ++j) {
            const float zj = fmaf((float)(-j), wc, kc[j]);  // k_j - j*w
            uk[j] = uc + kc[j];
            const float dl = M - zj;
            cf[j] = __expf(fminf(dl, 0.f));                 // carry factor
            df[j] = __expf(fminf(-dl, 0.f));                // new-term factor
            hh[j] = fmaf((float)(j - 1), wc, M);            // (j-1)w + M_j
            M = fmaxf(M, zj);
        }

        // inclusive chunk totals (pure fma chains) -> publish transform
        float Pt = 0.f, Qt = 0.f;
#pragma unroll
        for (int j = 0; j < CHUNK; ++j) {
            Pt = fmaf(cf[j], Pt, df[j] * vc[j]);
            Qt = fmaf(cf[j], Qt, df[j]);
        }
        if (wid < WAVES - 1) {
            Tp[sl][wid][lane] = Pt;
            Tq[sl][wid][lane] = Qt;
            To[sl][wid][lane] = fmaf((float)(CHUNK - 1), wc, M);
        }
        __syncthreads();

        // compose S_in = S_run ∘ T_0 ∘ ... ∘ T_{wid-1}
        float p = Sp[sl][lane], q = Sq[sl][lane], o = So[sl][lane];
        for (int j = 0; j < wid; ++j) {       // wave-uniform trip count
            const float Oj = To[sl][j][lane];
            const float a  = o + wCH;
            const float d  = a - Oj;
            const float e  = __expf(-fabsf(d));
            const float sA = d >= 0.f ? 1.f : e;
            const float sB = d >= 0.f ? e : 1.f;
            p = fmaf(sA, p, sB * Tp[sl][j][lane]);
            q = fmaf(sA, q, sB * Tq[sl][j][lane]);
            o = fmaxf(a, Oj);
        }

        // y loop: exact per-step normalizer; exclusive accumulators rerun
        const int tbase = s * SEG + wid * CHUNK;
        float aP = 0.f, aQ = 0.f;
#pragma unroll
        for (int j = 0; j < CHUNK; ++j) {
            const float g   = fmaf((float)j, wc, o);         // o + j*w
            const float no  = fmaxf(fmaxf(g, hh[j]), uk[j]);
            const float ea  = __expf(g - no);
            const float eb  = __expf(hh[j] - no);
            const float ec  = __expf(uk[j] - no);
            const float num = fmaf(ea, p, fmaf(eb, aP, ec * vc[j]));
            const float den = fmaf(ea, q, fmaf(eb, aQ, ec));
            yp[(size_t)(tbase + j) * CDIM] = __fdividef(num, den);
            aP = fmaf(cf[j], aP, df[j] * vc[j]);
            aQ = fmaf(cf[j], aQ, df[j]);
        }

        // new running state: last wave composes its own transform on top
        if (wid == WAVES - 1) {
            const float Ot = fmaf((float)(CHUNK - 1), wc, M);
            const float a  = o + wCH;
            const float d  = a - Ot;
            const float e  = __expf(-fabsf(d));
            const float sA = d >= 0.f ? 1.f : e;
            const float sB = d >= 0.f ? e : 1.f;
            Sp[1 - sl][lane] = fmaf(sA, p, sB * Pt);
            Sq[1 - sl][lane] = fmaf(sA, q, sB * Qt);
            So[1 - sl][lane] = fmaxf(a, Ot);
        }

        // prefetch segment s+2 into the freed buffer
        if (s + 2 < NSEG) {
            const int tn = tbase + 2 * SEG;
#pragma unroll
            for (int j = 0; j < CHUNK; ++j) {
                kc[j] = kp[(size_t)(tn + j) * CDIM];
                vc[j] = vp[(size_t)(tn + j) * CDIM];
            }
        }
        __builtin_amdgcn_sched_barrier(0);
    };

#pragma unroll 1
    for (int s2 = 0; s2 < NSEG; s2 += 2) {
        body(s2,     k0, v0);
        body(s2 + 1, k1, v1);
    }
}

extern "C" void kernel_launch(void* const* d_in, const int* in_sizes, int n_in,
                              void* d_out, int out_size, void* d_ws, size_t ws_size,
                              hipStream_t stream) {
    // inputs: 0=B, 1=T, 2=C (scalars), 3=w[C], 4=u[C], 5=k[B*T*C], 6=v[B*T*C]
    const float* w = (const float*)d_in[3];
    const float* u = (const float*)d_in[4];
    const float* k = (const float*)d_in[5];
    const float* v = (const float*)d_in[6];
    float* y = (float*)d_out;

    const int B = in_sizes[5] / (T_DIM * CDIM);   // 16

    dim3 grid(CDIM / 64, B);
    dim3 block(WAVES * 64);
    wkv_fwd_kernel<<<grid, block, 0, stream>>>(w, u, k, v, y);
}